// Round 7
// baseline (336.308 us; speedup 1.0000x reference)
//
#include <hip/hip_runtime.h>
#include <hip/hip_bf16.h>

// Problem constants: B=4, C=512, H=W=64 -> N=4096, CK=64
#define NB 4
#define CC 512
#define NN 4096
#define CKK 64

typedef _Float16 f16x4 __attribute__((ext_vector_type(4)));
typedef _Float16 f16x8 __attribute__((ext_vector_type(8)));
typedef float    f32x4 __attribute__((ext_vector_type(4)));

// ---------------------------------------------------------------------------
// async global->LDS, 16 B per lane. LDS dest is wave-uniform base + lane*16.
// ---------------------------------------------------------------------------
__device__ __forceinline__ void g2l16(const _Float16* g, _Float16* l) {
    __builtin_amdgcn_global_load_lds(
        (const __attribute__((address_space(1))) void*)g,
        (__attribute__((address_space(3))) void*)l, 16, 0, 0);
}

// Stage a 128-row x 32-col f16 tile (row stride ldg) into LDS [128][32] unpadded.
__device__ __forceinline__ void stage_tile(const _Float16* __restrict__ g, int ldg,
                                           _Float16* lds, int lane, int wave) {
    #pragma unroll
    for (int r = 0; r < 2; r++) {
        int q = r * 4 + wave;
        int row = q * 16 + (lane >> 2);
        int col = (lane & 3) * 8;
        g2l16(g + (size_t)row * ldg + col, lds + q * 512 + lane * 8);
    }
}

// ---------------------------------------------------------------------------
// K0 "prep": blocks 0..2047 transpose x (fp32 [B][C][N]) -> xT (f16 [B][N][C]);
// blocks 2048..2687 pack Wf/Wg/Wh -> Wall[640][512] f16 + Ball[640] fp32.
// ---------------------------------------------------------------------------
__launch_bounds__(256)
__global__ void prep(const float* __restrict__ x, _Float16* __restrict__ xT,
                     const float* __restrict__ Wf, const float* __restrict__ bf_,
                     const float* __restrict__ Wg, const float* __restrict__ bg_,
                     const float* __restrict__ Wh, const float* __restrict__ bh_,
                     _Float16* __restrict__ Wall, float* __restrict__ Ball) {
    const int N = NN, C = CC;
    int bid = blockIdx.x;
    int t = threadIdx.x;
    if (bid < 2048) {
        int n0 = (bid & 63) << 6;
        int c0 = ((bid >> 6) & 7) << 6;
        int b  = bid >> 9;
        __shared__ float T[64][65];
        const float* xb = x + (size_t)b * C * N;
        #pragma unroll
        for (int r = 0; r < 4; r++) {
            int c = (t >> 4) + 16 * r;
            int n4 = (t & 15) * 4;
            float4 v = *(const float4*)(xb + (size_t)(c0 + c) * N + n0 + n4);
            T[n4 + 0][c] = v.x; T[n4 + 1][c] = v.y; T[n4 + 2][c] = v.z; T[n4 + 3][c] = v.w;
        }
        __syncthreads();
        int n = t >> 2, cb = (t & 3) * 16;
        f16x8 h0, h1;
        #pragma unroll
        for (int i = 0; i < 8; i++) { h0[i] = (_Float16)T[n][cb + i]; h1[i] = (_Float16)T[n][cb + 8 + i]; }
        _Float16* dst = xT + (size_t)b * N * C + (size_t)(n0 + n) * C + c0 + cb;
        *(f16x8*)dst = h0;
        *(f16x8*)(dst + 8) = h1;
    } else {
        int o = bid - 2048;  // 0..639
        const float* src;
        if (o < 64)       src = Wf + (size_t)o * C;
        else if (o < 128) src = Wg + (size_t)(o - 64) * C;
        else              src = Wh + (size_t)(o - 128) * C;
        Wall[(size_t)o * C + t]       = (_Float16)src[t];
        Wall[(size_t)o * C + 256 + t] = (_Float16)src[256 + t];
        if (t == 0)
            Ball[o] = (o < 64) ? bf_[o] : (o < 128 ? bg_[o - 64] : bh_[o - 128]);
    }
}

// ---------------------------------------------------------------------------
// K1: projections, NT MFMA GEMM. Y[o][n] = sum_c Wall[o][c]*xT[n][c] + Ball[o]
// Both operands async-staged, K-contig. Outputs routed to Ft/Gt/Hx.
// ---------------------------------------------------------------------------
__launch_bounds__(256)
__global__ void proj_mfma(const _Float16* __restrict__ xT, const _Float16* __restrict__ Wall,
                          const float* __restrict__ Ball,
                          _Float16* __restrict__ Ft, _Float16* __restrict__ Gt,
                          _Float16* __restrict__ Hx) {
    const int N = NN, C = CC;
    int n0 = blockIdx.x * 128;
    int o0 = blockIdx.y * 128;
    int b  = blockIdx.z;
    const _Float16* Arow = Wall + (size_t)o0 * C;
    const _Float16* Brow = xT + (size_t)b * N * C + (size_t)n0 * C;
    __shared__ _Float16 As[128 * 32];
    __shared__ _Float16 Bs[128 * 32];
    int tid = threadIdx.x, lane = tid & 63, wave = tid >> 6;
    int wm = wave & 1, wn = wave >> 1, lrow = lane & 15, quad = lane >> 4;
    f32x4 acc[4][4] = {};
    for (int kc = 0; kc < C; kc += 32) {
        __syncthreads();
        stage_tile(Arow + kc, C, As, lane, wave);
        stage_tile(Brow + kc, C, Bs, lane, wave);
        __syncthreads();
        f16x8 af[4], bf[4];
        #pragma unroll
        for (int mi = 0; mi < 4; mi++)
            af[mi] = *(const f16x8*)(As + (wm * 64 + mi * 16 + lrow) * 32 + quad * 8);
        #pragma unroll
        for (int ni = 0; ni < 4; ni++)
            bf[ni] = *(const f16x8*)(Bs + (wn * 64 + ni * 16 + lrow) * 32 + quad * 8);
        #pragma unroll
        for (int mi = 0; mi < 4; mi++)
            #pragma unroll
            for (int ni = 0; ni < 4; ni++)
                acc[mi][ni] = __builtin_amdgcn_mfma_f32_16x16x32_f16(af[mi], bf[ni], acc[mi][ni], 0, 0, 0);
    }
    float bias_r[4][4];
    #pragma unroll
    for (int mi = 0; mi < 4; mi++)
        #pragma unroll
        for (int r = 0; r < 4; r++)
            bias_r[mi][r] = Ball[o0 + wm * 64 + mi * 16 + quad * 4 + r];
    _Float16* Ftb = Ft + (size_t)b * NN * CKK;
    _Float16* Gtb = Gt + (size_t)b * NN * CKK;
    _Float16* Hxb = Hx + (size_t)b * CC * N;
    #pragma unroll
    for (int mi = 0; mi < 4; mi++)
        #pragma unroll
        for (int ni = 0; ni < 4; ni++)
            #pragma unroll
            for (int r = 0; r < 4; r++) {
                int o = o0 + wm * 64 + mi * 16 + quad * 4 + r;
                int n = n0 + wn * 64 + ni * 16 + lrow;
                _Float16 v = (_Float16)(acc[mi][ni][r] + bias_r[mi][r]);
                if (o < 64)       Ftb[(size_t)n * CKK + o] = v;
                else if (o < 128) Gtb[(size_t)n * CKK + (o - 64)] = v;
                else              Hxb[(size_t)(o - 128) * N + n] = v;
            }
}

// ---------------------------------------------------------------------------
// K2: energy fused. S = Ft_tile . Gt_tile^T (K=64). Per-tile row max Mt via
// in-register + LDS reduce; P' = exp(s16 - Mt) f16, staged through LDS and
// stored COALESCED (f16x8, 256 B/row runs); Lpart = sum of stored P' values.
// ---------------------------------------------------------------------------
#define PST_LD 136   // Pst row stride (f16): 16B-aligned rows, quad-offset banks
__launch_bounds__(256)
__global__ void energy_fused(const _Float16* __restrict__ Ft, const _Float16* __restrict__ Gt,
                             _Float16* __restrict__ P, float* __restrict__ Mpart,
                             float* __restrict__ Lpart, int r0, int Rstr) {
    const int N = NN;
    int b = blockIdx.z;
    const _Float16* Arow = Ft + (size_t)b * N * CKK + (size_t)(r0 + blockIdx.y * 128) * CKK;
    const _Float16* Brow = Gt + (size_t)b * N * CKK + (size_t)(blockIdx.x * 128) * CKK;
    _Float16* Pb = P + (size_t)b * Rstr * N + (size_t)blockIdx.y * 128 * N + blockIdx.x * 128;
    __shared__ _Float16 As[128 * 32];
    __shared__ _Float16 Bs[128 * 32];
    __shared__ _Float16 Pst[128 * PST_LD];  // 34 KB staging for coalesced P store
    __shared__ float Sred[640];  // [0..255] M halves | [256..511] L halves | [512..639] Mt
    int tid = threadIdx.x, lane = tid & 63, wave = tid >> 6;
    int wm = wave & 1, wn = wave >> 1, lrow = lane & 15, quad = lane >> 4;
    f32x4 acc[4][4] = {};
    #pragma unroll
    for (int kc = 0; kc < CKK; kc += 32) {
        __syncthreads();
        stage_tile(Arow + kc, CKK, As, lane, wave);
        stage_tile(Brow + kc, CKK, Bs, lane, wave);
        __syncthreads();
        f16x8 af[4], bf[4];
        #pragma unroll
        for (int mi = 0; mi < 4; mi++)
            af[mi] = *(const f16x8*)(As + (wm * 64 + mi * 16 + lrow) * 32 + quad * 8);
        #pragma unroll
        for (int ni = 0; ni < 4; ni++)
            bf[ni] = *(const f16x8*)(Bs + (wn * 64 + ni * 16 + lrow) * 32 + quad * 8);
        #pragma unroll
        for (int mi = 0; mi < 4; mi++)
            #pragma unroll
            for (int ni = 0; ni < 4; ni++)
                acc[mi][ni] = __builtin_amdgcn_mfma_f32_16x16x32_f16(af[mi], bf[ni], acc[mi][ni], 0, 0, 0);
    }
    // row max over this wave's 64-col half
    float mloc[16];
    #pragma unroll
    for (int mi = 0; mi < 4; mi++)
        #pragma unroll
        for (int r = 0; r < 4; r++) {
            float v = acc[mi][0][r];
            #pragma unroll
            for (int ni = 1; ni < 4; ni++) v = fmaxf(v, acc[mi][ni][r]);
            mloc[mi * 4 + r] = v;
        }
    #pragma unroll
    for (int off = 1; off < 16; off <<= 1)
        #pragma unroll
        for (int s = 0; s < 16; s++)
            mloc[s] = fmaxf(mloc[s], __shfl_xor(mloc[s], off));
    {   // lane with lrow==s publishes slot s
        float v = mloc[0];
        #pragma unroll
        for (int s = 1; s < 16; s++) v = (lrow == s) ? mloc[s] : v;
        int row = wm * 64 + (lrow >> 2) * 16 + quad * 4 + (lrow & 3);
        Sred[wn * 128 + row] = v;
    }
    __syncthreads();
    if (tid < 128) Sred[512 + tid] = fmaxf(Sred[tid], Sred[128 + tid]);
    __syncthreads();
    // P' = exp(s16 - Mt) into LDS staging; Lpart sums the f16-rounded values
    float lloc[16];
    #pragma unroll
    for (int mi = 0; mi < 4; mi++)
        #pragma unroll
        for (int r = 0; r < 4; r++) {
            int row = wm * 64 + mi * 16 + quad * 4 + r;
            float m = Sred[512 + row];
            float s = 0.f;
            #pragma unroll
            for (int ni = 0; ni < 4; ni++) {
                int j = wn * 64 + ni * 16 + lrow;
                float s16 = (float)(_Float16)acc[mi][ni][r];
                _Float16 p16 = (_Float16)__expf(s16 - m);
                Pst[row * PST_LD + j] = p16;
                s += (float)p16;
            }
            lloc[mi * 4 + r] = s;
        }
    #pragma unroll
    for (int off = 1; off < 16; off <<= 1)
        #pragma unroll
        for (int s = 0; s < 16; s++)
            lloc[s] += __shfl_xor(lloc[s], off);
    {
        float v = lloc[0];
        #pragma unroll
        for (int s = 1; s < 16; s++) v = (lrow == s) ? lloc[s] : v;
        int row = wm * 64 + (lrow >> 2) * 16 + quad * 4 + (lrow & 3);
        Sred[256 + wn * 128 + row] = v;
    }
    __syncthreads();
    if (tid < 128) {
        size_t sidx = ((size_t)b * 32 + blockIdx.x) * Rstr + blockIdx.y * 128 + tid;
        Mpart[sidx] = Sred[512 + tid];
        Lpart[sidx] = Sred[256 + tid] + Sred[256 + 128 + tid];
    }
    // coalesced P store: each row emitted as 16 f16x8 segments (256 B runs)
    int col16 = tid & 15, rowb = tid >> 4;
    #pragma unroll
    for (int s = 0; s < 8; s++) {
        int row = rowb + s * 16;
        f16x8 v = *(const f16x8*)(Pst + row * PST_LD + col16 * 8);
        *(f16x8*)(Pb + (size_t)row * N + col16 * 8) = v;
    }
}

// ---------------------------------------------------------------------------
// K3: combine per-tile stats -> per-(row, j-tile) correction factor
// cfac[b][jt][i] = exp(Mt - m_row) / l_row  (f16). Then sum_j p = 1 exactly.
// ---------------------------------------------------------------------------
__launch_bounds__(256)
__global__ void combine_stats(const float* __restrict__ Mpart, const float* __restrict__ Lpart,
                              _Float16* __restrict__ cfac, int rows, int Rstr) {
    int b = blockIdx.y;
    int i = blockIdx.x * 256 + threadIdx.x;
    if (i >= rows) return;
    const float* mp = Mpart + (size_t)b * 32 * Rstr + i;
    const float* lp = Lpart + (size_t)b * 32 * Rstr + i;
    float m = -1e30f;
    #pragma unroll
    for (int jt = 0; jt < 32; jt++) m = fmaxf(m, mp[(size_t)jt * Rstr]);
    float l = 0.f;
    #pragma unroll
    for (int jt = 0; jt < 32; jt++)
        l += lp[(size_t)jt * Rstr] * __expf(mp[(size_t)jt * Rstr] - m);
    float linv = 1.0f / l;
    _Float16* cf = cfac + (size_t)b * 32 * Rstr + i;
    #pragma unroll
    for (int jt = 0; jt < 32; jt++)
        cf[(size_t)jt * Rstr] = (_Float16)(__expf(mp[(size_t)jt * Rstr] - m) * linv);
}

// ---------------------------------------------------------------------------
// K4: out MFMA. O[c][i] = sum_j Hx[c][j] * (P'[i][j] * cfac[i][jt])
// cfac applied as packed f16 muls on B fragments (LDS-cached, 8 KB).
// grid.x = c-tile (fastest) so consecutive blocks share the P i-tile in L2.
// epilogue: out = gamma*O + x (fp32)
// ---------------------------------------------------------------------------
__launch_bounds__(256)
__global__ void out_mfma(const _Float16* __restrict__ Hx, const _Float16* __restrict__ P,
                         const _Float16* __restrict__ cfac,
                         const float* __restrict__ x, const float* __restrict__ gamma,
                         float* __restrict__ out, int r0, int Rstr) {
    const int N = NN, C = CC;
    int b = blockIdx.z;
    int c0  = blockIdx.x * 128;
    int i0l = blockIdx.y * 128;
    const _Float16* Arow = Hx + (size_t)b * C * N + (size_t)c0 * N;
    const _Float16* Brow = P  + (size_t)b * Rstr * N + (size_t)i0l * N;
    __shared__ _Float16 As[128 * 32];
    __shared__ _Float16 Bs[128 * 32];
    __shared__ _Float16 Cf[32 * 128];   // [jt][i_local]
    int tid = threadIdx.x, lane = tid & 63, wave = tid >> 6;
    int wm = wave & 1, wn = wave >> 1, lrow = lane & 15, quad = lane >> 4;
    #pragma unroll
    for (int r = 0; r < 16; r++) {
        int idx = tid + r * 256;            // 0..4095
        int jt = idx >> 7, ii = idx & 127;
        Cf[idx] = cfac[((size_t)b * 32 + jt) * Rstr + i0l + ii];
    }
    __syncthreads();
    f32x4 acc[4][4] = {};
    for (int jt = 0; jt < 32; jt++) {
        _Float16 cfv[4];
        #pragma unroll
        for (int ni = 0; ni < 4; ni++)
            cfv[ni] = Cf[jt * 128 + wn * 64 + ni * 16 + lrow];
        #pragma unroll
        for (int kk = 0; kk < 4; kk++) {
            int kc = jt * 128 + kk * 32;
            __syncthreads();
            stage_tile(Arow + kc, N, As, lane, wave);
            stage_tile(Brow + kc, N, Bs, lane, wave);
            __syncthreads();
            f16x8 af[4], bf[4];
            #pragma unroll
            for (int mi = 0; mi < 4; mi++)
                af[mi] = *(const f16x8*)(As + (wm * 64 + mi * 16 + lrow) * 32 + quad * 8);
            #pragma unroll
            for (int ni = 0; ni < 4; ni++) {
                bf[ni] = *(const f16x8*)(Bs + (wn * 64 + ni * 16 + lrow) * 32 + quad * 8);
                #pragma unroll
                for (int j = 0; j < 8; j++) bf[ni][j] *= cfv[ni];
            }
            #pragma unroll
            for (int mi = 0; mi < 4; mi++)
                #pragma unroll
                for (int ni = 0; ni < 4; ni++)
                    acc[mi][ni] = __builtin_amdgcn_mfma_f32_16x16x32_f16(af[mi], bf[ni], acc[mi][ni], 0, 0, 0);
        }
    }
    float gv = gamma[0];
    const float* xb = x + (size_t)b * C * N;
    float* ob = out + (size_t)b * C * N;
    int ig0 = r0 + i0l;
    #pragma unroll
    for (int mi = 0; mi < 4; mi++)
        #pragma unroll
        for (int ni = 0; ni < 4; ni++)
            #pragma unroll
            for (int r = 0; r < 4; r++) {
                int c = c0 + wm * 64 + mi * 16 + quad * 4 + r;
                int i = ig0 + wn * 64 + ni * 16 + lrow;
                ob[(size_t)c * N + i] = gv * acc[mi][ni][r] + xb[(size_t)c * N + i];
            }
}

extern "C" void kernel_launch(void* const* d_in, const int* in_sizes, int n_in,
                              void* d_out, int out_size, void* d_ws, size_t ws_size,
                              hipStream_t stream) {
    const float* x     = (const float*)d_in[0];
    const float* Wf    = (const float*)d_in[1];
    const float* bf    = (const float*)d_in[2];
    const float* Wg    = (const float*)d_in[3];
    const float* bg    = (const float*)d_in[4];
    const float* Wh    = (const float*)d_in[5];
    const float* bh    = (const float*)d_in[6];
    const float* gamma = (const float*)d_in[7];
    float* out = (float*)d_out;

    const int B = NB, C = CC, N = NN;

    // Workspace layout (bytes):
    //   Wall [640][512] f16    @ 0        (640 KiB)
    //   Ball [640]      fp32   @ 768 KiB
    //   Ft   [B][N][64] f16    @ 1 MiB    (2 MiB)
    //   Gt   [B][N][64] f16    @ 3 MiB    (2 MiB)
    //   Hx   [B][C][N]  f16    @ 5 MiB    (16 MiB)
    //   Mpart[B][32][R] f32    @ 21 MiB   (<=2 MiB)
    //   Lpart[B][32][R] f32    @ 23 MiB   (<=2 MiB)
    //   cfac [B][32][R] f16    @ 25 MiB   (<=1 MiB)
    //   P    [B][R][N]  f16    @ 26 MiB   (chunk, auto-sized; 134 MiB at R=4096)
    //   xT   [B][N][C]  f16    @ 26 MiB   (17 MiB, ALIASES P: dead after proj)
    char* wsb = (char*)d_ws;
    _Float16* Wall = (_Float16*)wsb;
    float*    Ball = (float*)(wsb + ((size_t)768 << 10));
    _Float16* Ft = (_Float16*)(wsb + ((size_t)1 << 20));
    _Float16* Gt = (_Float16*)(wsb + ((size_t)3 << 20));
    _Float16* Hx = (_Float16*)(wsb + ((size_t)5 << 20));
    float* Mpart = (float*)(wsb + ((size_t)21 << 20));
    float* Lpart = (float*)(wsb + ((size_t)23 << 20));
    _Float16* cfac = (_Float16*)(wsb + ((size_t)25 << 20));
    _Float16* P  = (_Float16*)(wsb + ((size_t)26 << 20));
    _Float16* xT = P;  // alias: xT consumed by proj before P is written
    size_t base = (size_t)26 << 20;
    size_t avail = (ws_size > base) ? ws_size - base : 0;
    size_t bytesPer128 = (size_t)B * N * 2 * 128;  // 4 MiB per 128 rows of P
    int R = (int)(avail / bytesPer128) * 128;
    if (R > N) R = N;
    if (R < 128) R = 128;

    prep<<<dim3(2048 + 640), dim3(256), 0, stream>>>(
        x, xT, Wf, bf, Wg, bg, Wh, bh, Wall, Ball);
    proj_mfma<<<dim3(N / 128, 5, B), dim3(256), 0, stream>>>(xT, Wall, Ball, Ft, Gt, Hx);

    for (int r0 = 0; r0 < N; r0 += R) {
        int rows = (R < N - r0) ? R : (N - r0);
        energy_fused<<<dim3(N / 128, rows / 128, B), dim3(256), 0, stream>>>(
            Ft, Gt, P, Mpart, Lpart, r0, R);
        combine_stats<<<dim3((rows + 255) / 256, B), dim3(256), 0, stream>>>(
            Mpart, Lpart, cfac, rows, R);
        out_mfma<<<dim3(C / 128, rows / 128, B), dim3(256), 0, stream>>>(
            Hx, P, cfac, x, gamma, out, r0, R);
    }
}

// Round 8
// 268.516 us; speedup vs baseline: 1.2525x; 1.2525x over previous
//
#include <hip/hip_runtime.h>
#include <hip/hip_bf16.h>

// Problem constants: B=4, C=512, H=W=64 -> N=4096, CK=64
#define NB 4
#define CC 512
#define NN 4096
#define CKK 64

typedef _Float16 f16x4 __attribute__((ext_vector_type(4)));
typedef _Float16 f16x8 __attribute__((ext_vector_type(8)));
typedef float    f32x4 __attribute__((ext_vector_type(4)));

// ---------------------------------------------------------------------------
// async global->LDS, 16 B per lane. LDS dest is wave-uniform base + lane*16.
// ---------------------------------------------------------------------------
__device__ __forceinline__ void g2l16(const _Float16* g, _Float16* l) {
    __builtin_amdgcn_global_load_lds(
        (const __attribute__((address_space(1))) void*)g,
        (__attribute__((address_space(3))) void*)l, 16, 0, 0);
}

// Stage a 128-row x 32-col f16 tile (row stride ldg) into LDS [128][32] unpadded.
__device__ __forceinline__ void stage_tile(const _Float16* __restrict__ g, int ldg,
                                           _Float16* lds, int lane, int wave) {
    #pragma unroll
    for (int r = 0; r < 2; r++) {
        int q = r * 4 + wave;
        int row = q * 16 + (lane >> 2);
        int col = (lane & 3) * 8;
        g2l16(g + (size_t)row * ldg + col, lds + q * 512 + lane * 8);
    }
}

// ---------------------------------------------------------------------------
// K0 "prep": blocks 0..2047 transpose x (fp32 [B][C][N]) -> xT (f16 [B][N][C]);
// blocks 2048..2687 pack Wf/Wg/Wh -> Wall[640][512] f16 + Ball[640] fp32.
// ---------------------------------------------------------------------------
__launch_bounds__(256)
__global__ void prep(const float* __restrict__ x, _Float16* __restrict__ xT,
                     const float* __restrict__ Wf, const float* __restrict__ bf_,
                     const float* __restrict__ Wg, const float* __restrict__ bg_,
                     const float* __restrict__ Wh, const float* __restrict__ bh_,
                     _Float16* __restrict__ Wall, float* __restrict__ Ball) {
    const int N = NN, C = CC;
    int bid = blockIdx.x;
    int t = threadIdx.x;
    if (bid < 2048) {
        int n0 = (bid & 63) << 6;
        int c0 = ((bid >> 6) & 7) << 6;
        int b  = bid >> 9;
        __shared__ float T[64][65];
        const float* xb = x + (size_t)b * C * N;
        #pragma unroll
        for (int r = 0; r < 4; r++) {
            int c = (t >> 4) + 16 * r;
            int n4 = (t & 15) * 4;
            float4 v = *(const float4*)(xb + (size_t)(c0 + c) * N + n0 + n4);
            T[n4 + 0][c] = v.x; T[n4 + 1][c] = v.y; T[n4 + 2][c] = v.z; T[n4 + 3][c] = v.w;
        }
        __syncthreads();
        int n = t >> 2, cb = (t & 3) * 16;
        f16x8 h0, h1;
        #pragma unroll
        for (int i = 0; i < 8; i++) { h0[i] = (_Float16)T[n][cb + i]; h1[i] = (_Float16)T[n][cb + 8 + i]; }
        _Float16* dst = xT + (size_t)b * N * C + (size_t)(n0 + n) * C + c0 + cb;
        *(f16x8*)dst = h0;
        *(f16x8*)(dst + 8) = h1;
    } else {
        int o = bid - 2048;  // 0..639
        const float* src;
        if (o < 64)       src = Wf + (size_t)o * C;
        else if (o < 128) src = Wg + (size_t)(o - 64) * C;
        else              src = Wh + (size_t)(o - 128) * C;
        Wall[(size_t)o * C + t]       = (_Float16)src[t];
        Wall[(size_t)o * C + 256 + t] = (_Float16)src[256 + t];
        if (t == 0)
            Ball[o] = (o < 64) ? bf_[o] : (o < 128 ? bg_[o - 64] : bh_[o - 128]);
    }
}

// ---------------------------------------------------------------------------
// K1: projections, NT MFMA GEMM. Y[o][n] = sum_c Wall[o][c]*xT[n][c] + Ball[o]
// Both operands async-staged, K-contig. Outputs routed to Ft/Gt/Hx.
// ---------------------------------------------------------------------------
__launch_bounds__(256)
__global__ void proj_mfma(const _Float16* __restrict__ xT, const _Float16* __restrict__ Wall,
                          const float* __restrict__ Ball,
                          _Float16* __restrict__ Ft, _Float16* __restrict__ Gt,
                          _Float16* __restrict__ Hx) {
    const int N = NN, C = CC;
    int n0 = blockIdx.x * 128;
    int o0 = blockIdx.y * 128;
    int b  = blockIdx.z;
    const _Float16* Arow = Wall + (size_t)o0 * C;
    const _Float16* Brow = xT + (size_t)b * N * C + (size_t)n0 * C;
    __shared__ _Float16 As[128 * 32];
    __shared__ _Float16 Bs[128 * 32];
    int tid = threadIdx.x, lane = tid & 63, wave = tid >> 6;
    int wm = wave & 1, wn = wave >> 1, lrow = lane & 15, quad = lane >> 4;
    f32x4 acc[4][4] = {};
    for (int kc = 0; kc < C; kc += 32) {
        __syncthreads();
        stage_tile(Arow + kc, C, As, lane, wave);
        stage_tile(Brow + kc, C, Bs, lane, wave);
        __syncthreads();
        f16x8 af[4], bf[4];
        #pragma unroll
        for (int mi = 0; mi < 4; mi++)
            af[mi] = *(const f16x8*)(As + (wm * 64 + mi * 16 + lrow) * 32 + quad * 8);
        #pragma unroll
        for (int ni = 0; ni < 4; ni++)
            bf[ni] = *(const f16x8*)(Bs + (wn * 64 + ni * 16 + lrow) * 32 + quad * 8);
        #pragma unroll
        for (int mi = 0; mi < 4; mi++)
            #pragma unroll
            for (int ni = 0; ni < 4; ni++)
                acc[mi][ni] = __builtin_amdgcn_mfma_f32_16x16x32_f16(af[mi], bf[ni], acc[mi][ni], 0, 0, 0);
    }
    float bias_r[4][4];
    #pragma unroll
    for (int mi = 0; mi < 4; mi++)
        #pragma unroll
        for (int r = 0; r < 4; r++)
            bias_r[mi][r] = Ball[o0 + wm * 64 + mi * 16 + quad * 4 + r];
    _Float16* Ftb = Ft + (size_t)b * NN * CKK;
    _Float16* Gtb = Gt + (size_t)b * NN * CKK;
    _Float16* Hxb = Hx + (size_t)b * CC * N;
    #pragma unroll
    for (int mi = 0; mi < 4; mi++)
        #pragma unroll
        for (int ni = 0; ni < 4; ni++)
            #pragma unroll
            for (int r = 0; r < 4; r++) {
                int o = o0 + wm * 64 + mi * 16 + quad * 4 + r;
                int n = n0 + wn * 64 + ni * 16 + lrow;
                _Float16 v = (_Float16)(acc[mi][ni][r] + bias_r[mi][r]);
                if (o < 64)       Ftb[(size_t)n * CKK + o] = v;
                else if (o < 128) Gtb[(size_t)n * CKK + (o - 64)] = v;
                else              Hxb[(size_t)(o - 128) * N + n] = v;
            }
}

// ---------------------------------------------------------------------------
// K2: energy fused. S = Ft_tile . Gt_tile^T (K=64). Per-tile row max Mt via
// in-register + LDS reduce; P' = exp(s16 - Mt) f16, staged through LDS and
// stored COALESCED (f16x8, 256 B/row runs); Lpart = sum of stored P' values.
// ---------------------------------------------------------------------------
#define PST_LD 136   // Pst row stride (f16): 16B-aligned rows, quad-offset banks
__launch_bounds__(256)
__global__ void energy_fused(const _Float16* __restrict__ Ft, const _Float16* __restrict__ Gt,
                             _Float16* __restrict__ P, float* __restrict__ Mpart,
                             float* __restrict__ Lpart, int r0, int Rstr) {
    const int N = NN;
    int b = blockIdx.z;
    const _Float16* Arow = Ft + (size_t)b * N * CKK + (size_t)(r0 + blockIdx.y * 128) * CKK;
    const _Float16* Brow = Gt + (size_t)b * N * CKK + (size_t)(blockIdx.x * 128) * CKK;
    _Float16* Pb = P + (size_t)b * Rstr * N + (size_t)blockIdx.y * 128 * N + blockIdx.x * 128;
    __shared__ _Float16 As[128 * 32];
    __shared__ _Float16 Bs[128 * 32];
    __shared__ _Float16 Pst[128 * PST_LD];  // 34 KB staging for coalesced P store
    __shared__ float Sred[640];  // [0..255] M halves | [256..511] L halves | [512..639] Mt
    int tid = threadIdx.x, lane = tid & 63, wave = tid >> 6;
    int wm = wave & 1, wn = wave >> 1, lrow = lane & 15, quad = lane >> 4;
    f32x4 acc[4][4] = {};
    #pragma unroll
    for (int kc = 0; kc < CKK; kc += 32) {
        __syncthreads();
        stage_tile(Arow + kc, CKK, As, lane, wave);
        stage_tile(Brow + kc, CKK, Bs, lane, wave);
        __syncthreads();
        f16x8 af[4], bf[4];
        #pragma unroll
        for (int mi = 0; mi < 4; mi++)
            af[mi] = *(const f16x8*)(As + (wm * 64 + mi * 16 + lrow) * 32 + quad * 8);
        #pragma unroll
        for (int ni = 0; ni < 4; ni++)
            bf[ni] = *(const f16x8*)(Bs + (wn * 64 + ni * 16 + lrow) * 32 + quad * 8);
        #pragma unroll
        for (int mi = 0; mi < 4; mi++)
            #pragma unroll
            for (int ni = 0; ni < 4; ni++)
                acc[mi][ni] = __builtin_amdgcn_mfma_f32_16x16x32_f16(af[mi], bf[ni], acc[mi][ni], 0, 0, 0);
    }
    // row max over this wave's 64-col half
    float mloc[16];
    #pragma unroll
    for (int mi = 0; mi < 4; mi++)
        #pragma unroll
        for (int r = 0; r < 4; r++) {
            float v = acc[mi][0][r];
            #pragma unroll
            for (int ni = 1; ni < 4; ni++) v = fmaxf(v, acc[mi][ni][r]);
            mloc[mi * 4 + r] = v;
        }
    #pragma unroll
    for (int off = 1; off < 16; off <<= 1)
        #pragma unroll
        for (int s = 0; s < 16; s++)
            mloc[s] = fmaxf(mloc[s], __shfl_xor(mloc[s], off));
    {   // lane with lrow==s publishes slot s
        float v = mloc[0];
        #pragma unroll
        for (int s = 1; s < 16; s++) v = (lrow == s) ? mloc[s] : v;
        int row = wm * 64 + (lrow >> 2) * 16 + quad * 4 + (lrow & 3);
        Sred[wn * 128 + row] = v;
    }
    __syncthreads();
    if (tid < 128) Sred[512 + tid] = fmaxf(Sred[tid], Sred[128 + tid]);
    __syncthreads();
    // P' = exp(s16 - Mt) into LDS staging; Lpart sums the f16-rounded values
    float lloc[16];
    #pragma unroll
    for (int mi = 0; mi < 4; mi++)
        #pragma unroll
        for (int r = 0; r < 4; r++) {
            int row = wm * 64 + mi * 16 + quad * 4 + r;
            float m = Sred[512 + row];
            float s = 0.f;
            #pragma unroll
            for (int ni = 0; ni < 4; ni++) {
                int j = wn * 64 + ni * 16 + lrow;
                float s16 = (float)(_Float16)acc[mi][ni][r];
                _Float16 p16 = (_Float16)__expf(s16 - m);
                Pst[row * PST_LD + j] = p16;
                s += (float)p16;
            }
            lloc[mi * 4 + r] = s;
        }
    #pragma unroll
    for (int off = 1; off < 16; off <<= 1)
        #pragma unroll
        for (int s = 0; s < 16; s++)
            lloc[s] += __shfl_xor(lloc[s], off);
    {
        float v = lloc[0];
        #pragma unroll
        for (int s = 1; s < 16; s++) v = (lrow == s) ? lloc[s] : v;
        int row = wm * 64 + (lrow >> 2) * 16 + quad * 4 + (lrow & 3);
        Sred[256 + wn * 128 + row] = v;
    }
    __syncthreads();
    if (tid < 128) {
        size_t sidx = ((size_t)b * 32 + blockIdx.x) * Rstr + blockIdx.y * 128 + tid;
        Mpart[sidx] = Sred[512 + tid];
        Lpart[sidx] = Sred[256 + tid] + Sred[256 + 128 + tid];
    }
    // coalesced P store: each row emitted as 16 f16x8 segments (256 B runs)
    int col16 = tid & 15, rowb = tid >> 4;
    #pragma unroll
    for (int s = 0; s < 8; s++) {
        int row = rowb + s * 16;
        f16x8 v = *(const f16x8*)(Pst + row * PST_LD + col16 * 8);
        *(f16x8*)(Pb + (size_t)row * N + col16 * 8) = v;
    }
}

// ---------------------------------------------------------------------------
// K4: out MFMA. O[c][i] = sum_j Hx[c][j] * (P'[i][j] * cfac[i][jt])
// Preamble computes cfac = exp(Mt - m_row)/l_row for this block's 128 rows
// directly from Mpart/Lpart (combine_stats folded in). cfac applied as packed
// f16 muls on B fragments. grid: i-tile FASTEST — the 4 c-tile blocks sharing
// a P i-tile have IDs differing by 32 (=0 mod 8) -> same XCD -> P L2-shared.
// epilogue: out = gamma*O + x (fp32)
// ---------------------------------------------------------------------------
__launch_bounds__(256)
__global__ void out_mfma(const _Float16* __restrict__ Hx, const _Float16* __restrict__ P,
                         const float* __restrict__ Mpart, const float* __restrict__ Lpart,
                         const float* __restrict__ x, const float* __restrict__ gamma,
                         float* __restrict__ out, int r0, int Rstr) {
    const int N = NN, C = CC;
    int b = blockIdx.z;
    int i0l = blockIdx.x * 128;
    int c0  = blockIdx.y * 128;
    const _Float16* Arow = Hx + (size_t)b * C * N + (size_t)c0 * N;
    const _Float16* Brow = P  + (size_t)b * Rstr * N + (size_t)i0l * N;
    __shared__ _Float16 As[128 * 32];
    __shared__ _Float16 Bs[128 * 32];
    __shared__ _Float16 Cf[32 * 128];   // [jt][i_local]
    int tid = threadIdx.x, lane = tid & 63, wave = tid >> 6;
    int wm = wave & 1, wn = wave >> 1, lrow = lane & 15, quad = lane >> 4;
    // --- preamble: fold combine_stats. Threads 0..127 each own one row. ---
    if (tid < 128) {
        const float* mp = Mpart + (size_t)b * 32 * Rstr + i0l + tid;
        const float* lp = Lpart + (size_t)b * 32 * Rstr + i0l + tid;
        float mv[32];
        float m = -1e30f;
        #pragma unroll
        for (int jt = 0; jt < 32; jt++) { mv[jt] = mp[(size_t)jt * Rstr]; m = fmaxf(m, mv[jt]); }
        float l = 0.f;
        #pragma unroll
        for (int jt = 0; jt < 32; jt++) {
            float e = __expf(mv[jt] - m);
            mv[jt] = e;
            l += lp[(size_t)jt * Rstr] * e;
        }
        float linv = 1.0f / l;
        #pragma unroll
        for (int jt = 0; jt < 32; jt++)
            Cf[jt * 128 + tid] = (_Float16)(mv[jt] * linv);
    }
    __syncthreads();
    f32x4 acc[4][4] = {};
    for (int jt = 0; jt < 32; jt++) {
        _Float16 cfv[4];
        #pragma unroll
        for (int ni = 0; ni < 4; ni++)
            cfv[ni] = Cf[jt * 128 + wn * 64 + ni * 16 + lrow];
        #pragma unroll
        for (int kk = 0; kk < 4; kk++) {
            int kc = jt * 128 + kk * 32;
            __syncthreads();
            stage_tile(Arow + kc, N, As, lane, wave);
            stage_tile(Brow + kc, N, Bs, lane, wave);
            __syncthreads();
            f16x8 af[4], bf[4];
            #pragma unroll
            for (int mi = 0; mi < 4; mi++)
                af[mi] = *(const f16x8*)(As + (wm * 64 + mi * 16 + lrow) * 32 + quad * 8);
            #pragma unroll
            for (int ni = 0; ni < 4; ni++) {
                bf[ni] = *(const f16x8*)(Bs + (wn * 64 + ni * 16 + lrow) * 32 + quad * 8);
                #pragma unroll
                for (int j = 0; j < 8; j++) bf[ni][j] *= cfv[ni];
            }
            #pragma unroll
            for (int mi = 0; mi < 4; mi++)
                #pragma unroll
                for (int ni = 0; ni < 4; ni++)
                    acc[mi][ni] = __builtin_amdgcn_mfma_f32_16x16x32_f16(af[mi], bf[ni], acc[mi][ni], 0, 0, 0);
        }
    }
    float gv = gamma[0];
    const float* xb = x + (size_t)b * C * N;
    float* ob = out + (size_t)b * C * N;
    int ig0 = r0 + i0l;
    #pragma unroll
    for (int mi = 0; mi < 4; mi++)
        #pragma unroll
        for (int ni = 0; ni < 4; ni++)
            #pragma unroll
            for (int r = 0; r < 4; r++) {
                int c = c0 + wm * 64 + mi * 16 + quad * 4 + r;
                int i = ig0 + wn * 64 + ni * 16 + lrow;
                ob[(size_t)c * N + i] = gv * acc[mi][ni][r] + xb[(size_t)c * N + i];
            }
}

extern "C" void kernel_launch(void* const* d_in, const int* in_sizes, int n_in,
                              void* d_out, int out_size, void* d_ws, size_t ws_size,
                              hipStream_t stream) {
    const float* x     = (const float*)d_in[0];
    const float* Wf    = (const float*)d_in[1];
    const float* bf    = (const float*)d_in[2];
    const float* Wg    = (const float*)d_in[3];
    const float* bg    = (const float*)d_in[4];
    const float* Wh    = (const float*)d_in[5];
    const float* bh    = (const float*)d_in[6];
    const float* gamma = (const float*)d_in[7];
    float* out = (float*)d_out;

    const int B = NB, C = CC, N = NN;

    // Workspace layout (bytes):
    //   Wall [640][512] f16    @ 0        (640 KiB)
    //   Ball [640]      fp32   @ 768 KiB
    //   Ft   [B][N][64] f16    @ 1 MiB    (2 MiB)
    //   Gt   [B][N][64] f16    @ 3 MiB    (2 MiB)
    //   Hx   [B][C][N]  f16    @ 5 MiB    (16 MiB)
    //   Mpart[B][32][R] f32    @ 21 MiB   (<=2 MiB)
    //   Lpart[B][32][R] f32    @ 23 MiB   (<=2 MiB)
    //   P    [B][R][N]  f16    @ 26 MiB   (chunk, auto-sized; 134 MiB at R=4096)
    //   xT   [B][N][C]  f16    @ 26 MiB   (17 MiB, ALIASES P: dead after proj)
    char* wsb = (char*)d_ws;
    _Float16* Wall = (_Float16*)wsb;
    float*    Ball = (float*)(wsb + ((size_t)768 << 10));
    _Float16* Ft = (_Float16*)(wsb + ((size_t)1 << 20));
    _Float16* Gt = (_Float16*)(wsb + ((size_t)3 << 20));
    _Float16* Hx = (_Float16*)(wsb + ((size_t)5 << 20));
    float* Mpart = (float*)(wsb + ((size_t)21 << 20));
    float* Lpart = (float*)(wsb + ((size_t)23 << 20));
    _Float16* P  = (_Float16*)(wsb + ((size_t)26 << 20));
    _Float16* xT = P;  // alias: xT consumed by proj before P is written
    size_t base = (size_t)26 << 20;
    size_t avail = (ws_size > base) ? ws_size - base : 0;
    size_t bytesPer128 = (size_t)B * N * 2 * 128;  // 4 MiB per 128 rows of P
    int R = (int)(avail / bytesPer128) * 128;
    if (R > N) R = N;
    if (R < 128) R = 128;

    prep<<<dim3(2048 + 640), dim3(256), 0, stream>>>(
        x, xT, Wf, bf, Wg, bg, Wh, bh, Wall, Ball);
    proj_mfma<<<dim3(N / 128, 5, B), dim3(256), 0, stream>>>(xT, Wall, Ball, Ft, Gt, Hx);

    for (int r0 = 0; r0 < N; r0 += R) {
        int rows = (R < N - r0) ? R : (N - r0);
        energy_fused<<<dim3(N / 128, rows / 128, B), dim3(256), 0, stream>>>(
            Ft, Gt, P, Mpart, Lpart, r0, R);
        out_mfma<<<dim3(rows / 128, C / 128, B), dim3(256), 0, stream>>>(
            Hx, P, Mpart, Lpart, x, gamma, out, r0, R);
    }
}